// Round 1
// 2005.234 us; speedup vs baseline: 1.3728x; 1.3728x over previous
//
#include <hip/hip_runtime.h>
#include <hip/hip_bf16.h>
#include <stdint.h>

// ---------------------------------------------------------------------------
// Attention_53712861003822 : B=4 S=1024 D=4096, HQ=32 HKV=8 HD=128, GQA 4:1
// Round 5: attn LDS bank-conflict fix. rocprof showed SQ_LDS_BANK_CONFLICT =
// 5.16e8 cycles (~70% of attn kernel lifetime) -- all from the phase-3 V
// transpose store (inter-lane stride 8*VP*2 = 1408B == 0 mod 128B -> 32-way
// conflict). Fix: XOR-swizzle kk by ((d>>3)&7)<<3 (preserves 8-short
// alignment of the b128 reads; spreads store lanes across 8 banks).
// Secondary: fp32 GEMM staging now uses float4 loads + packed bf16 cvt.
// Memory plan: ws[0,32MB)=Qb (attn in-place); d_out[0,8MB)=Kb, [8,16MB)=Vb
// (dead before the final GEMM overwrites d_out).
// ---------------------------------------------------------------------------

typedef __attribute__((ext_vector_type(8))) short s8_t;     // 8 x bf16
typedef __attribute__((ext_vector_type(4))) float f4_t;     // MFMA acc

#define MFMA16(a, b, c) __builtin_amdgcn_mfma_f32_16x16x32_bf16((a), (b), (c), 0, 0, 0)

__device__ __forceinline__ float b2f(unsigned short u) {
  union { unsigned int i; float f; } x; x.i = ((unsigned int)u) << 16; return x.f;
}
__device__ __forceinline__ unsigned short f2b(float f) {
  union { float f; unsigned int i; } x; x.f = f;
  unsigned int r = x.i + 0x7fff + ((x.i >> 16) & 1);   // RNE
  return (unsigned short)(r >> 16);
}

// Probe: interpret first 64 ushorts of p as bf16. Genuine bf16 inputs here are
// all |v| <= ~1. fp32 data's low mantissa halves are ~random 16-bit patterns:
// P(trigger) per sample ~0.4 -> miss probability ~1e-14 over 64.
__device__ __forceinline__ bool probe_is_f32(const void* p) {
  if (!p) return false;
  const unsigned short* u = (const unsigned short*)p;
  bool f = false;
#pragma unroll
  for (int i = 0; i < 64; ++i) {
    const float v = b2f(u[i]);
    f |= !(fabsf(v) < 1e8f);      // catches huge exponents AND NaN
  }
  return f;
}

// 8 consecutive elements starting at elem offset `off` (must be 8-aligned),
// returned as bf16x8. f32=true: read fp32 (vectorized float4) and round RNE
// via the packed cvt path; else raw bf16.
__device__ __forceinline__ s8_t load8(const void* base, size_t off, bool f32) {
  if (f32) {
    const float* p = (const float*)base + off;
    const float4 a = *(const float4*)(p);
    const float4 b = *(const float4*)(p + 4);
    union { s8_t v; __hip_bfloat162 h[4]; } t;
    t.h[0] = __float22bfloat162_rn(make_float2(a.x, a.y));
    t.h[1] = __float22bfloat162_rn(make_float2(a.z, a.w));
    t.h[2] = __float22bfloat162_rn(make_float2(b.x, b.y));
    t.h[3] = __float22bfloat162_rn(make_float2(b.z, b.w));
    return t.v;
  }
  return *(const s8_t*)((const unsigned short*)base + off);
}

// ---------------------------------------------------------------------------
// C[M,N] = A[M,K] @ B[N,K]^T  (row-major, fp32 acc). A/B fp32-or-bf16 per
// probe; C bf16 (probeC=null) or fp32. 128x128 tile, BK=64, 4 waves x 4x4
// MFMA tiles. LDS [128][72]: 144B row stride -> 2-way bank alias (free).
// ---------------------------------------------------------------------------
__global__ __launch_bounds__(256) void gemm_bt(
    void* __restrict__ C,
    const void* __restrict__ A,
    const void* __restrict__ B,
    int M, int N, int K,
    const void* probeA, const void* probeB, const void* probeC)
{
  constexpr int LP = 72;
  __shared__ unsigned short sA[128 * LP];
  __shared__ unsigned short sB[128 * LP];
  const bool fA = probe_is_f32(probeA);
  const bool fB = probe_is_f32(probeB);
  const bool fC = probe_is_f32(probeC);

  const int tid  = threadIdx.x;
  const int lane = tid & 63;
  const int wv   = tid >> 6;
  const int wr   = (wv >> 1) * 64;
  const int wc   = (wv & 1) * 64;
  const int quad = lane >> 4;
  const int l16  = lane & 15;
  const int m0 = blockIdx.x * 128;
  const int n0 = blockIdx.y * 128;

  f4_t acc[4][4];
#pragma unroll
  for (int i = 0; i < 4; ++i)
#pragma unroll
    for (int j = 0; j < 4; ++j) acc[i][j] = (f4_t){0.f, 0.f, 0.f, 0.f};

  int srow[4], scol[4];
#pragma unroll
  for (int it = 0; it < 4; ++it) {
    const int s = it * 256 + tid;
    srow[it] = s >> 3;
    scol[it] = (s & 7) * 8;
  }

  const int nK = K >> 6;
  for (int kt = 0; kt < nK; ++kt) {
    const int k0 = kt << 6;
    s8_t va[4], vb[4];
#pragma unroll
    for (int it = 0; it < 4; ++it) {
      va[it] = load8(A, (size_t)(m0 + srow[it]) * K + k0 + scol[it], fA);
      vb[it] = load8(B, (size_t)(n0 + srow[it]) * K + k0 + scol[it], fB);
    }
#pragma unroll
    for (int it = 0; it < 4; ++it) {
      *(s8_t*)(&sA[srow[it] * LP + scol[it]]) = va[it];
      *(s8_t*)(&sB[srow[it] * LP + scol[it]]) = vb[it];
    }
    __syncthreads();
#pragma unroll
    for (int kc = 0; kc < 2; ++kc) {
      s8_t af[4], bf[4];
#pragma unroll
      for (int i = 0; i < 4; ++i) {
        af[i] = *(const s8_t*)(&sA[(wr + i * 16 + l16) * LP + (kc * 4 + quad) * 8]);
        bf[i] = *(const s8_t*)(&sB[(wc + i * 16 + l16) * LP + (kc * 4 + quad) * 8]);
      }
#pragma unroll
      for (int i = 0; i < 4; ++i)
#pragma unroll
        for (int j = 0; j < 4; ++j)
          acc[i][j] = MFMA16(af[i], bf[j], acc[i][j]);
    }
    __syncthreads();
  }

  // epilogue: C/D layout col = lane&15, row = quad*4 + reg
#pragma unroll
  for (int i = 0; i < 4; ++i) {
    const int rbase = m0 + wr + i * 16 + quad * 4;
#pragma unroll
    for (int j = 0; j < 4; ++j) {
      const int col = n0 + wc + j * 16 + l16;
#pragma unroll
      for (int rg = 0; rg < 4; ++rg) {
        const size_t idx = (size_t)(rbase + rg) * N + col;
        if (fC) ((float*)C)[idx] = acc[i][j][rg];
        else    ((unsigned short*)C)[idx] = f2b(acc[i][j][rg]);
      }
    }
  }
}

// ---------------------------------------------------------------------------
// RoPE in-place on bf16 X = (B,S,nh,128). cos/sin adaptive (fp32 or bf16).
// Reference: out[j] = x[j]*cos[s,64+j] - x[64+j]*sin[s,64+j], etc.
// ---------------------------------------------------------------------------
__global__ __launch_bounds__(256) void rope_kernel(
    unsigned short* __restrict__ X,
    const void* __restrict__ cosb,
    const void* __restrict__ sinb,
    int log2nh, const void* probe)
{
  const bool f = probe_is_f32(probe);
  const size_t idx = (size_t)blockIdx.x * 256 + threadIdx.x;
  const int j = (int)(idx & 63);
  const size_t row = idx >> 6;                 // (b*S+s)*nh + h
  const int s = (int)((row >> log2nh) & 1023);
  const int ci = s * 128 + 64 + j;
  const float c  = f ? ((const float*)cosb)[ci] : b2f(((const unsigned short*)cosb)[ci]);
  const float sn = f ? ((const float*)sinb)[ci] : b2f(((const unsigned short*)sinb)[ci]);
  unsigned short* p = X + row * 128;
  const float x1 = b2f(p[j]);
  const float x2 = b2f(p[64 + j]);
  p[j]      = f2b(x1 * c - x2 * sn);
  p[64 + j] = f2b(x2 * c + x1 * sn);
}

// ---------------------------------------------------------------------------
// Attention (all-bf16 buffers): one block per (b, h, 16 q-rows), S=1024.
// O may alias Q (in-place): Q tile fully read into LDS before O writes;
// per-block write-set == read-set.
// sv is XOR-swizzled: element (d, kk) lives at sv[d*VP + (kk ^ ((d>>3)&7)<<3)].
// The XOR touches only bits 3-5 of kk, so 8-short-aligned b128 reads remain
// contiguous+aligned; the transpose store's 16 l16-lanes (stride 8*VP shorts
// == 0 mod 64 dwords, previously ONE bank) now spread across 8 banks.
// ---------------------------------------------------------------------------
__global__ __launch_bounds__(256) void attn_kernel(
    unsigned short* O,
    const unsigned short* Q,
    const unsigned short* __restrict__ Kb,
    const unsigned short* __restrict__ Vb)
{
  constexpr int S = 1024, HQ = 32, HKV = 8, HD = 128;
  constexpr int SCP = 1048;
  constexpr int QP  = 152;
  constexpr int VP  = 88;
  constexpr float SCALE = 0.08838834764831845f;  // 1/sqrt(128)
  __shared__ unsigned short sc[16 * SCP];
  __shared__ unsigned short sq[16 * QP];
  __shared__ unsigned short sv[128 * VP];
  __shared__ float s_linv[16];

  const int bid = blockIdx.x;
  const int qt = bid & 63;
  const int h  = (bid >> 6) & 31;
  const int b  = bid >> 11;
  const int kh = h >> 2;
  const int tid  = threadIdx.x;
  const int lane = tid & 63;
  const int wv   = tid >> 6;
  const int quad = lane >> 4;
  const int l16  = lane & 15;

  const unsigned short* Qg = Q  + ((size_t)(b * S + qt * 16) * HQ + h) * HD;
  const unsigned short* Kg = Kb + ((size_t)b * S * HKV + kh) * HD;
  const unsigned short* Vg = Vb + ((size_t)b * S * HKV + kh) * HD;

  {
    const int r = tid >> 4, c = (tid & 15) * 8;
    *(s8_t*)(&sq[r * QP + c]) = *(const s8_t*)(Qg + (size_t)r * (HQ * HD) + c);
  }
  __syncthreads();

  // ---- phase 1: scores ----
#pragma unroll 1
  for (int kt = 0; kt < 16; ++kt) {
    const int ks = wv * 256 + kt * 16;
    f4_t acc = (f4_t){0.f, 0.f, 0.f, 0.f};
#pragma unroll
    for (int kc = 0; kc < 4; ++kc) {
      const s8_t qa = *(const s8_t*)(&sq[l16 * QP + kc * 32 + quad * 8]);
      const s8_t kf = *(const s8_t*)(Kg + (size_t)(ks + l16) * (HKV * HD) + kc * 32 + quad * 8);
      acc = MFMA16(qa, kf, acc);
    }
#pragma unroll
    for (int rg = 0; rg < 4; ++rg)
      sc[(quad * 4 + rg) * SCP + ks + l16] = f2b(acc[rg] * SCALE);
  }
  __syncthreads();

  // ---- phase 2: softmax ----
  {
    const int r = tid >> 4, c0 = tid & 15;
    float mx = -1e30f;
#pragma unroll 4
    for (int u = 0; u < 64; ++u)
      mx = fmaxf(mx, b2f(sc[r * SCP + c0 + u * 16]));
#pragma unroll
    for (int off = 8; off; off >>= 1) mx = fmaxf(mx, __shfl_xor(mx, off, 16));
    float sum = 0.f;
#pragma unroll 4
    for (int u = 0; u < 64; ++u) {
      const int idx = r * SCP + c0 + u * 16;
      const float e = __expf(b2f(sc[idx]) - mx);
      sum += e;
      sc[idx] = f2b(e);
    }
#pragma unroll
    for (int off = 8; off; off >>= 1) sum += __shfl_xor(sum, off, 16);
    if (c0 == 0) s_linv[r] = 1.0f / sum;
  }
  __syncthreads();

  // ---- phase 3: O = P @ V ----
  f4_t oacc[2];
  oacc[0] = (f4_t){0.f, 0.f, 0.f, 0.f};
  oacc[1] = (f4_t){0.f, 0.f, 0.f, 0.f};
#pragma unroll 1
  for (int ck = 0; ck < 16; ++ck) {
    if (ck) __syncthreads();
#pragma unroll
    for (int it = 0; it < 4; ++it) {
      const int s  = it * 256 + tid;
      const int kk = s >> 4;
      const int c  = (s & 15) * 8;          // d-base for this lane
      const int sw = (s & 7) << 3;          // == ((d>>3)&7)<<3 for d in [c, c+8)
      const s8_t v = *(const s8_t*)(Vg + (size_t)(ck * 64 + kk) * (HKV * HD) + c);
#pragma unroll
      for (int jj = 0; jj < 8; ++jj)
        sv[(c + jj) * VP + (kk ^ sw)] = ((const unsigned short*)&v)[jj];
    }
    __syncthreads();
#pragma unroll
    for (int kc = 0; kc < 2; ++kc) {
      const s8_t pa = *(const s8_t*)(&sc[l16 * SCP + ck * 64 + kc * 32 + quad * 8]);
#pragma unroll
      for (int dt = 0; dt < 2; ++dt) {
        const int d2 = wv * 32 + dt * 16 + l16;
        const s8_t vf = *(const s8_t*)(
            &sv[d2 * VP + ((kc * 32 + quad * 8) ^ (((d2 >> 3) & 7) << 3))]);
        oacc[dt] = MFMA16(pa, vf, oacc[dt]);
      }
    }
  }

#pragma unroll
  for (int dt = 0; dt < 2; ++dt)
#pragma unroll
    for (int rg = 0; rg < 4; ++rg) {
      const int r = quad * 4 + rg;
      const int d = wv * 32 + dt * 16 + l16;
      O[((size_t)(b * S + qt * 16 + r) * HQ + h) * HD + d] =
          f2b(oacc[dt][rg] * s_linv[r]);
    }
}

// ---------------------------------------------------------------------------
extern "C" void kernel_launch(void* const* d_in, const int* in_sizes, int n_in,
                              void* d_out, int out_size, void* d_ws, size_t ws_size,
                              hipStream_t stream)
{
  (void)in_sizes; (void)n_in; (void)out_size; (void)ws_size;
  const void* hs   = d_in[0];
  const void* cosb = d_in[1];
  const void* sinb = d_in[2];
  const void* Wq   = d_in[3];
  const void* Wk   = d_in[4];
  const void* Wv   = d_in[5];
  const void* Wo   = d_in[6];

  // Internal bf16 scratch:
  //   Qb : ws[0,32MB)      (attn output in-place)
  //   Kb : d_out[0,8MB), Vb : d_out[8,16MB)  -- dead before final GEMM
  unsigned short* Qb = (unsigned short*)d_ws;
  unsigned short* Kb = (unsigned short*)d_out;
  unsigned short* Vb = (unsigned short*)d_out + (size_t)4194304;

  gemm_bt<<<dim3(32,  8), 256, 0, stream>>>(Kb, hs, Wk, 4096, 1024, 4096, hs, hs, nullptr);
  gemm_bt<<<dim3(32,  8), 256, 0, stream>>>(Vb, hs, Wv, 4096, 1024, 4096, hs, hs, nullptr);
  gemm_bt<<<dim3(32, 32), 256, 0, stream>>>(Qb, hs, Wq, 4096, 4096, 4096, hs, hs, nullptr);
  rope_kernel<<<32768, 256, 0, stream>>>(Qb, cosb, sinb, 5, hs);
  rope_kernel<<< 8192, 256, 0, stream>>>(Kb, cosb, sinb, 3, hs);
  attn_kernel<<<4 * 32 * 64, 256, 0, stream>>>(Qb, Qb, Kb, Vb);
  // final projection: A=Qb (bf16), B=Wo (adaptive), C=d_out (adaptive dtype)
  gemm_bt<<<dim3(32, 32), 256, 0, stream>>>(d_out, Qb, Wo, 4096, 4096, 4096,
                                            nullptr, hs, hs);
}

// Round 3
// 1938.808 us; speedup vs baseline: 1.4198x; 1.0343x over previous
//
#include <hip/hip_runtime.h>
#include <hip/hip_bf16.h>
#include <stdint.h>

// ---------------------------------------------------------------------------
// Attention_53712861003822 : B=4 S=1024 D=4096, HQ=32 HKV=8 HD=128, GQA 4:1
// Round 7 = Round 6 + rope dtype-probe fix.
//  Round-6 bug: probe_is_f32(cos) read floats that are exactly 1.0 (row s=0)
//  -> indistinguishable from bf16 -> rope read fp32 as bf16 -> NaN.
//  Fix: probe cos AND sin at ushort offset 2048 (float row s=8, nontrivial
//  mantissas); host overrides via in_sizes[1] when it matches a known size.
//  (a) V GEMM writes V TRANSPOSED (Vt[kh*128+d][b*1024+s]) -> attn phase-3
//      reads V direct from global (L2-resident). No sv LDS, no ph-3 barriers.
//  (b) softmax + rope vectorized (b128).
//  (c) one-shot bf16 conversion of hs (d_out[16,48M)), Wq (ws[32,64M)),
//      Wo (ws[64,96M)) when sizes permit -- halves GEMM staging bytes.
// Memory plan (fp32 mode): ws[0,32M)=Qb; d_out[0,8M)=Kb, [8,16M)=Vt,
// [16,48M)=hs_b (dead before final GEMM overwrites d_out).
// ---------------------------------------------------------------------------

typedef __attribute__((ext_vector_type(8))) short s8_t;     // 8 x bf16
typedef __attribute__((ext_vector_type(4))) float f4_t;     // MFMA acc
typedef __attribute__((ext_vector_type(4))) unsigned short us4_t;

#define MFMA16(a, b, c) __builtin_amdgcn_mfma_f32_16x16x32_bf16((a), (b), (c), 0, 0, 0)

__device__ __forceinline__ float b2f(unsigned short u) {
  union { unsigned int i; float f; } x; x.i = ((unsigned int)u) << 16; return x.f;
}
__device__ __forceinline__ unsigned short f2b(float f) {
  union { float f; unsigned int i; } x; x.f = f;
  unsigned int r = x.i + 0x7fff + ((x.i >> 16) & 1);   // RNE
  return (unsigned short)(r >> 16);
}

// Probe 64 ushorts at `off` as bf16; large-exponent/NaN patterns => fp32 data.
__device__ __forceinline__ bool probe_is_f32_off(const void* p, int off) {
  if (!p) return false;
  const unsigned short* u = (const unsigned short*)p + off;
  bool f = false;
#pragma unroll
  for (int i = 0; i < 64; ++i) {
    const float v = b2f(u[i]);
    f |= !(fabsf(v) < 1e8f);      // catches huge exponents AND NaN
  }
  return f;
}
__device__ __forceinline__ bool probe_is_f32(const void* p) {
  return probe_is_f32_off(p, 0);
}

__device__ __forceinline__ s8_t cvt8(const float* p) {
  const float4 a = *(const float4*)(p);
  const float4 b = *(const float4*)(p + 4);
  union { s8_t v; __hip_bfloat162 h[4]; } t;
  t.h[0] = __float22bfloat162_rn(make_float2(a.x, a.y));
  t.h[1] = __float22bfloat162_rn(make_float2(a.z, a.w));
  t.h[2] = __float22bfloat162_rn(make_float2(b.x, b.y));
  t.h[3] = __float22bfloat162_rn(make_float2(b.z, b.w));
  return t.v;
}

// 8 consecutive elements starting at elem offset `off` (8-aligned) as bf16x8.
__device__ __forceinline__ s8_t load8(const void* base, size_t off, bool f32) {
  if (f32) return cvt8((const float*)base + off);
  return *(const s8_t*)((const unsigned short*)base + off);
}

// ---------------------------------------------------------------------------
// One-shot fp32->bf16 (or bf16 copy) conversion, 8 elems/thread.
// ---------------------------------------------------------------------------
__global__ __launch_bounds__(256) void cvt_to_bf16(
    unsigned short* __restrict__ out, const void* __restrict__ in)
{
  const bool f = probe_is_f32(in);
  const size_t i = ((size_t)blockIdx.x * 256 + threadIdx.x) * 8;
  if (f) *(s8_t*)(out + i) = cvt8((const float*)in + i);
  else   *(s8_t*)(out + i) = *(const s8_t*)((const unsigned short*)in + i);
}

// ---------------------------------------------------------------------------
// C[M,N] = A[M,K] @ B[N,K]^T  (row-major, fp32 acc). A/B fp32-or-bf16 per
// probe; C bf16 (probeC=null) or fp32. transC: write C^T (bf16 only), packed
// 4-row us4 stores -> Ct[n][m] layout. 128x128 tile, BK=64, 4 waves.
// ---------------------------------------------------------------------------
__global__ __launch_bounds__(256) void gemm_bt(
    void* __restrict__ C,
    const void* __restrict__ A,
    const void* __restrict__ B,
    int M, int N, int K,
    const void* probeA, const void* probeB, const void* probeC,
    int transC)
{
  constexpr int LP = 72;
  __shared__ unsigned short sA[128 * LP];
  __shared__ unsigned short sB[128 * LP];
  const bool fA = probe_is_f32(probeA);
  const bool fB = probe_is_f32(probeB);
  const bool fC = probe_is_f32(probeC);

  const int tid  = threadIdx.x;
  const int lane = tid & 63;
  const int wv   = tid >> 6;
  const int wr   = (wv >> 1) * 64;
  const int wc   = (wv & 1) * 64;
  const int quad = lane >> 4;
  const int l16  = lane & 15;
  const int m0 = blockIdx.x * 128;
  const int n0 = blockIdx.y * 128;

  f4_t acc[4][4];
#pragma unroll
  for (int i = 0; i < 4; ++i)
#pragma unroll
    for (int j = 0; j < 4; ++j) acc[i][j] = (f4_t){0.f, 0.f, 0.f, 0.f};

  int srow[4], scol[4];
#pragma unroll
  for (int it = 0; it < 4; ++it) {
    const int s = it * 256 + tid;
    srow[it] = s >> 3;
    scol[it] = (s & 7) * 8;
  }

  const int nK = K >> 6;
  for (int kt = 0; kt < nK; ++kt) {
    const int k0 = kt << 6;
    s8_t va[4], vb[4];
#pragma unroll
    for (int it = 0; it < 4; ++it) {
      va[it] = load8(A, (size_t)(m0 + srow[it]) * K + k0 + scol[it], fA);
      vb[it] = load8(B, (size_t)(n0 + srow[it]) * K + k0 + scol[it], fB);
    }
#pragma unroll
    for (int it = 0; it < 4; ++it) {
      *(s8_t*)(&sA[srow[it] * LP + scol[it]]) = va[it];
      *(s8_t*)(&sB[srow[it] * LP + scol[it]]) = vb[it];
    }
    __syncthreads();
#pragma unroll
    for (int kc = 0; kc < 2; ++kc) {
      s8_t af[4], bf[4];
#pragma unroll
      for (int i = 0; i < 4; ++i) {
        af[i] = *(const s8_t*)(&sA[(wr + i * 16 + l16) * LP + (kc * 4 + quad) * 8]);
        bf[i] = *(const s8_t*)(&sB[(wc + i * 16 + l16) * LP + (kc * 4 + quad) * 8]);
      }
#pragma unroll
      for (int i = 0; i < 4; ++i)
#pragma unroll
        for (int j = 0; j < 4; ++j)
          acc[i][j] = MFMA16(af[i], bf[j], acc[i][j]);
    }
    __syncthreads();
  }

  // epilogue: C/D layout col = lane&15, row = quad*4 + reg
  if (transC) {
#pragma unroll
    for (int i = 0; i < 4; ++i) {
      const int rbase = m0 + wr + i * 16 + quad * 4;
#pragma unroll
      for (int j = 0; j < 4; ++j) {
        const int col = n0 + wc + j * 16 + l16;
        us4_t t;
#pragma unroll
        for (int rg = 0; rg < 4; ++rg) t[rg] = f2b(acc[i][j][rg]);
        *(us4_t*)(&((unsigned short*)C)[(size_t)col * M + rbase]) = t;
      }
    }
  } else {
#pragma unroll
    for (int i = 0; i < 4; ++i) {
      const int rbase = m0 + wr + i * 16 + quad * 4;
#pragma unroll
      for (int j = 0; j < 4; ++j) {
        const int col = n0 + wc + j * 16 + l16;
#pragma unroll
        for (int rg = 0; rg < 4; ++rg) {
          const size_t idx = (size_t)(rbase + rg) * N + col;
          if (fC) ((float*)C)[idx] = acc[i][j][rg];
          else    ((unsigned short*)C)[idx] = f2b(acc[i][j][rg]);
        }
      }
    }
  }
}

// ---------------------------------------------------------------------------
// RoPE in-place on bf16 X = (B,S,nh,128), vectorized 8 elems/thread.
// out[j] = x[j]*cos[s,64+j] - x[64+j]*sin[s,64+j]; out[64+j] = x2*c + x1*s.
// mode: 0 = device probe (offset 2048, cos|sin), 1 = force fp32, 2 = bf16.
// ---------------------------------------------------------------------------
__global__ __launch_bounds__(256) void rope_kernel(
    unsigned short* __restrict__ X,
    const void* __restrict__ cosb,
    const void* __restrict__ sinb,
    int log2nh, int mode)
{
  bool f;
  if (mode == 1)      f = true;
  else if (mode == 2) f = false;
  else f = probe_is_f32_off(cosb, 2048) | probe_is_f32_off(sinb, 2048);
  const size_t idx = (size_t)blockIdx.x * 256 + threadIdx.x;
  const int jb = (int)(idx & 7) * 8;
  const size_t row = idx >> 3;                 // (b*S+s)*nh + h
  const int s = (int)((row >> log2nh) & 1023);
  unsigned short* p = X + row * 128;
  union { s8_t v; unsigned short u[8]; } ua, ub, o1, o2;
  ua.v = *(const s8_t*)(p + jb);
  ub.v = *(const s8_t*)(p + 64 + jb);
#pragma unroll
  for (int j = 0; j < 8; ++j) {
    const int ci = s * 128 + 64 + jb + j;
    const float c  = f ? ((const float*)cosb)[ci] : b2f(((const unsigned short*)cosb)[ci]);
    const float sn = f ? ((const float*)sinb)[ci] : b2f(((const unsigned short*)sinb)[ci]);
    const float x1 = b2f(ua.u[j]);
    const float x2 = b2f(ub.u[j]);
    o1.u[j] = f2b(x1 * c - x2 * sn);
    o2.u[j] = f2b(x2 * c + x1 * sn);
  }
  *(s8_t*)(p + jb)      = o1.v;
  *(s8_t*)(p + 64 + jb) = o2.v;
}

// ---------------------------------------------------------------------------
// Attention: one block per (b, h, 16 q-rows), S=1024. O aliases Q (in-place).
// K read direct from global (row-major [b,s,kh,d], L2-resident 256KB/panel).
// V read direct from global in TRANSPOSED layout Vt[kh*128+d][b*1024+s]:
// the PV B-fragment (8 consecutive k at fixed d) is one contiguous 16B load;
// 4 quads x 16B fill full 64B lines. No V LDS, no phase-3 barriers.
// ---------------------------------------------------------------------------
__global__ __launch_bounds__(256) void attn_kernel(
    unsigned short* O,
    const unsigned short* Q,
    const unsigned short* __restrict__ Kb,
    const unsigned short* __restrict__ Vt)
{
  constexpr int S = 1024, HQ = 32, HKV = 8, HD = 128;
  constexpr int SCP = 1048;
  constexpr int QP  = 152;
  constexpr float SCALE = 0.08838834764831845f;  // 1/sqrt(128)
  __shared__ unsigned short sc[16 * SCP];
  __shared__ unsigned short sq[16 * QP];
  __shared__ float s_linv[16];

  const int bid = blockIdx.x;
  const int qt = bid & 63;
  const int h  = (bid >> 6) & 31;
  const int b  = bid >> 11;
  const int kh = h >> 2;
  const int tid  = threadIdx.x;
  const int lane = tid & 63;
  const int wv   = tid >> 6;
  const int quad = lane >> 4;
  const int l16  = lane & 15;

  const unsigned short* Qg = Q  + ((size_t)(b * S + qt * 16) * HQ + h) * HD;
  const unsigned short* Kg = Kb + ((size_t)b * S * HKV + kh) * HD;
  const unsigned short* Vg = Vt + ((size_t)kh * HD) * 4096 + (size_t)b * S;

  {
    const int r = tid >> 4, c = (tid & 15) * 8;
    *(s8_t*)(&sq[r * QP + c]) = *(const s8_t*)(Qg + (size_t)r * (HQ * HD) + c);
  }
  __syncthreads();

  // ---- phase 1: scores (K direct from global) ----
#pragma unroll 2
  for (int kt = 0; kt < 16; ++kt) {
    const int ks = wv * 256 + kt * 16;
    f4_t acc = (f4_t){0.f, 0.f, 0.f, 0.f};
#pragma unroll
    for (int kc = 0; kc < 4; ++kc) {
      const s8_t qa = *(const s8_t*)(&sq[l16 * QP + kc * 32 + quad * 8]);
      const s8_t kf = *(const s8_t*)(Kg + (size_t)(ks + l16) * (HKV * HD) + kc * 32 + quad * 8);
      acc = MFMA16(qa, kf, acc);
    }
#pragma unroll
    for (int rg = 0; rg < 4; ++rg)
      sc[(quad * 4 + rg) * SCP + ks + l16] = f2b(acc[rg] * SCALE);
  }
  __syncthreads();

  // ---- phase 2: softmax (vectorized b128 row passes) ----
  {
    const int r = tid >> 4, c0 = tid & 15;
    unsigned short* srow = &sc[r * SCP + c0 * 8];
    float mx = -1e30f;
#pragma unroll
    for (int u = 0; u < 8; ++u) {
      union { s8_t v; unsigned short us[8]; } t;
      t.v = *(const s8_t*)(srow + u * 128);
#pragma unroll
      for (int j = 0; j < 8; ++j) mx = fmaxf(mx, b2f(t.us[j]));
    }
#pragma unroll
    for (int off = 8; off; off >>= 1) mx = fmaxf(mx, __shfl_xor(mx, off, 16));
    float sum = 0.f;
#pragma unroll
    for (int u = 0; u < 8; ++u) {
      union { s8_t v; unsigned short us[8]; } t;
      t.v = *(const s8_t*)(srow + u * 128);
#pragma unroll
      for (int j = 0; j < 8; ++j) {
        const float e = __expf(b2f(t.us[j]) - mx);
        sum += e;
        t.us[j] = f2b(e);
      }
      *(s8_t*)(srow + u * 128) = t.v;
    }
#pragma unroll
    for (int off = 8; off; off >>= 1) sum += __shfl_xor(sum, off, 16);
    if (c0 == 0) s_linv[r] = 1.0f / sum;
  }
  __syncthreads();

  // ---- phase 3: O = P @ Vt (V direct from global, no barriers) ----
  f4_t oacc[2];
  oacc[0] = (f4_t){0.f, 0.f, 0.f, 0.f};
  oacc[1] = (f4_t){0.f, 0.f, 0.f, 0.f};
  const unsigned short* vb0 = Vg + (size_t)(wv * 32 + l16) * 4096 + quad * 8;
  const unsigned short* vb1 = vb0 + (size_t)16 * 4096;
  const unsigned short* prow = &sc[l16 * SCP + quad * 8];
#pragma unroll 2
  for (int ck = 0; ck < 16; ++ck) {
#pragma unroll
    for (int kc = 0; kc < 2; ++kc) {
      const int ko = ck * 64 + kc * 32;
      const s8_t pa = *(const s8_t*)(prow + ko);
      const s8_t v0 = *(const s8_t*)(vb0 + ko);
      const s8_t v1 = *(const s8_t*)(vb1 + ko);
      oacc[0] = MFMA16(pa, v0, oacc[0]);
      oacc[1] = MFMA16(pa, v1, oacc[1]);
    }
  }

#pragma unroll
  for (int dt = 0; dt < 2; ++dt)
#pragma unroll
    for (int rg = 0; rg < 4; ++rg) {
      const int r = quad * 4 + rg;
      const int d = wv * 32 + dt * 16 + l16;
      O[((size_t)(b * S + qt * 16 + r) * HQ + h) * HD + d] =
          f2b(oacc[dt][rg] * s_linv[r]);
    }
}

// ---------------------------------------------------------------------------
extern "C" void kernel_launch(void* const* d_in, const int* in_sizes, int n_in,
                              void* d_out, int out_size, void* d_ws, size_t ws_size,
                              hipStream_t stream)
{
  const void* hs   = d_in[0];
  const void* cosb = d_in[1];
  const void* sinb = d_in[2];
  const void* Wq   = d_in[3];
  const void* Wk   = d_in[4];
  const void* Wv   = d_in[5];
  const void* Wo   = d_in[6];

  const size_t MB = (size_t)1 << 20;
  // fp32 input mode <=> hs is (4,1024,4096) fp32 = 64MB (bf16 mode: 32MB).
  const bool f32in = (n_in >= 1 && in_sizes && in_sizes[0] == (int)(64 * MB));
  // cos/sin dtype for rope: decide host-side when sizes match; else probe.
  int rmode = 0;
  if (in_sizes && n_in >= 2) {
    if (in_sizes[1] == 524288) rmode = 1;        // (1,1024,128) fp32
    else if (in_sizes[1] == 262144) rmode = 2;   // (1,1024,128) bf16
  }

  unsigned short* Qb = (unsigned short*)d_ws;                    // ws[0,32M)
  unsigned short* Kb = (unsigned short*)d_out;                   // d_out[0,8M)
  unsigned short* Vt = (unsigned short*)d_out + 4194304;         // d_out[8,16M)

  // One-shot bf16 operand conversion (fp32 mode only; layout gated on sizes).
  const void* hsA = hs;
  if (f32in && out_size >= (int)(48 * MB)) {
    unsigned short* hs_b = (unsigned short*)d_out + 8388608;     // d_out[16,48M)
    cvt_to_bf16<<<8192, 256, 0, stream>>>(hs_b, hs);
    hsA = hs_b;
  }
  const void* WqB = Wq;
  if (f32in && ws_size >= 64 * MB) {
    unsigned short* wq_b = (unsigned short*)d_ws + 16777216;     // ws[32,64M)
    cvt_to_bf16<<<8192, 256, 0, stream>>>(wq_b, Wq);
    WqB = wq_b;
  }
  const void* WoB = Wo;
  if (f32in && ws_size >= 96 * MB) {
    unsigned short* wo_b = (unsigned short*)d_ws + 33554432;     // ws[64,96M)
    cvt_to_bf16<<<8192, 256, 0, stream>>>(wo_b, Wo);
    WoB = wo_b;
  }

  gemm_bt<<<dim3(32,  8), 256, 0, stream>>>(Kb, hsA, Wk, 4096, 1024, 4096,
                                            hsA, Wk, nullptr, 0);
  gemm_bt<<<dim3(32,  8), 256, 0, stream>>>(Vt, hsA, Wv, 4096, 1024, 4096,
                                            hsA, Wv, nullptr, 1);
  gemm_bt<<<dim3(32, 32), 256, 0, stream>>>(Qb, hsA, WqB, 4096, 4096, 4096,
                                            hsA, WqB, nullptr, 0);
  rope_kernel<<<4096, 256, 0, stream>>>(Qb, cosb, sinb, 5, rmode);
  rope_kernel<<<1024, 256, 0, stream>>>(Kb, cosb, sinb, 3, rmode);
  attn_kernel<<<4 * 32 * 64, 256, 0, stream>>>(Qb, Qb, Kb, Vt);
  // final projection: A=Qb (bf16), B=Wo(/bf16 copy), C=d_out (input dtype)
  gemm_bt<<<dim3(32, 32), 256, 0, stream>>>(d_out, Qb, WoB, 4096, 4096, 4096,
                                            nullptr, WoB, hs, 0);
}